// Round 9
// baseline (131.104 us; speedup 1.0000x reference)
//
#include <hip/hip_runtime.h>
#include <hip/hip_bf16.h>
#include <stdint.h>

typedef __attribute__((ext_vector_type(8))) short bf16x8;
typedef __attribute__((ext_vector_type(4))) float f32x4;

#define B_ROWS 131072
#define BM 16
#define NT 16
#define GRID 512        // 512 * 16 * 16 = 131072 rows

// LDS map (bytes). x buffers: 16 rows * 1024B; h buffers: 16 rows * 1280B.
#define XB 16384
#define HB 20480
#define H_OFF 32768     // X0@0, X1@16384, H0@32768, H1@53248
#define A1_OFF 73728    // 16 * 136 * 2 = 4352
#define LSUM_OFF 78080  // 64 f32
#define LDS_TOTAL 78336 // -> 2 blocks/CU (156672 <= 163840)
#define AP 136          // a1/a2 bf16 row pitch

// packed weight fragment offsets (uint4 units)
#define W1P_OFF 0
#define W2P_OFF 7168
#define W3P_OFF 9216

typedef const __attribute__((address_space(1))) unsigned int gu32;
typedef __attribute__((address_space(3))) unsigned int lu32;

__device__ inline void gl_lds16(const void* g, void* l) {
  __builtin_amdgcn_global_load_lds((gu32*)g, (lu32*)l, 16, 0, 0);
}

__device__ inline uint16_t f2bf(float x) {
  uint32_t u = __float_as_uint(x);
  u += 0x7fffu + ((u >> 16) & 1u);   // RNE
  return (uint16_t)(u >> 16);
}

__device__ inline float tanh_fast(float x) {
  x = fminf(fmaxf(x, -15.f), 15.f);
  float e = __expf(2.f * x);
  return (e - 1.f) / (e + 1.f);
}

__global__ void prepack_kernel(const float* __restrict__ W1,
                               const float* __restrict__ W2,
                               const float* __restrict__ W3,
                               uint4* __restrict__ wp) {
  int tid = blockIdx.x * 256 + threadIdx.x;
  if (tid >= 13312) return;
  int l = tid & 63, f = tid >> 6;
  const float* W; int N, kt, nt;
  if (f < 112)      { W = W1; N = 128; int ff = f;       nt = ff / 14; kt = ff - nt * 14; }
  else if (f < 144) { W = W2; N = 128; int ff = f - 112; nt = ff >> 2; kt = ff & 3; }
  else              { W = W3; N = 256; int ff = f - 144; nt = ff >> 2; kt = ff & 3; }
  int k0  = kt * 32 + (l >> 4) * 8;
  int col = nt * 16 + (l & 15);
  uint16_t v[8];
#pragma unroll
  for (int j = 0; j < 8; j++) v[j] = f2bf(W[(size_t)(k0 + j) * N + col]);
  uint4 o;
  o.x = (uint32_t)v[0] | ((uint32_t)v[1] << 16);
  o.y = (uint32_t)v[2] | ((uint32_t)v[3] << 16);
  o.z = (uint32_t)v[4] | ((uint32_t)v[5] << 16);
  o.w = (uint32_t)v[6] | ((uint32_t)v[7] << 16);
  wp[tid] = o;
}

__global__ __launch_bounds__(256, 2) void fused_kernel(
    const float* __restrict__ x, const float* __restrict__ h,
    const float* __restrict__ b1, const float* __restrict__ b2,
    const float* __restrict__ b3, const uint4* __restrict__ wp,
    float* __restrict__ y, float* __restrict__ ldet) {
  extern __shared__ uint8_t smem[];
  uint16_t* a1   = (uint16_t*)(smem + A1_OFF);
  float*    lsum = (float*)(smem + LSUM_OFF);

  const int t = threadIdx.x;
  const int wid = t >> 6, l = t & 63;
  const int lr = l & 15, lq = l >> 4;   // lr in [0,16)
  const int tile0 = blockIdx.x * NT;

  // ---- precompute per-lane staging source offsets (tile-relative, f32 units)
  // chunk c stored at within-row slot (c&~15)|((c&15)^(row&15)) -- XOR involution,
  // so the source for slot `lane` is chunk f(lane). Dest stays linear (gload rule).
  int xoff[4], hoff[5];
#pragma unroll
  for (int k = 0; k < 4; k++) {
    int r = wid * 4 + k;                       // one row per instruction
    int c = (l & ~15) | ((l & 15) ^ (r & 15));
    xoff[k] = r * 256 + c * 4;
  }
#pragma unroll
  for (int k = 0; k < 5; k++) {
    int s = (wid * 5 + k) * 64 + l;            // slot in [0,1280)
    int r = s / 80, cp = s - r * 80;
    int c = (cp & ~15) | ((cp & 15) ^ (r & 15));
    hoff[k] = r * 320 + c * 4;
  }

  // ---- prologue: async-stage tile 0 into buffer 0
  {
    const float* xg = x + (size_t)(tile0 * BM) * 256;
    const float* hg = h + (size_t)(tile0 * BM) * 320;
#pragma unroll
    for (int k = 0; k < 4; k++)
      gl_lds16(xg + xoff[k], smem + (wid * 4 + k) * 1024);
#pragma unroll
    for (int k = 0; k < 5; k++)
      gl_lds16(hg + hoff[k], smem + H_OFF + (wid * 5 + k) * 1024);
  }

  int cur = 0;
  for (int it = 0; it < NT; ++it) {
    const int m0 = (tile0 + it) * BM;
    __syncthreads();   // TOP: drains vmcnt -> buffer `cur` staged & visible

    const uint8_t* xsc = smem + cur * XB;
    const uint8_t* hsc = smem + H_OFF + cur * HB;
    uint16_t* a2 = (uint16_t*)(smem + H_OFF + cur * HB);  // alias dead h[cur] after G1

    // ---- issue async stage of tile it+1 into buffer cur^1 (zero registers)
    if (it + 1 < NT) {
      const float* xg = x + (size_t)(m0 + BM) * 256;
      const float* hg = h + (size_t)(m0 + BM) * 320;
      uint8_t* xd = smem + (cur ^ 1) * XB;
      uint8_t* hd = smem + H_OFF + (cur ^ 1) * HB;
#pragma unroll
      for (int k = 0; k < 4; k++)
        gl_lds16(xg + xoff[k], xd + (wid * 4 + k) * 1024);
#pragma unroll
      for (int k = 0; k < 5; k++)
        gl_lds16(hg + hoff[k], hd + (wid * 5 + k) * 1024);
    }

    // ---- GEMM1: a1 = relu(z(16x448) @ W1 + b1); z = [x_even | h], cvt on read
    {
      f32x4 acc[2] = {};
#pragma unroll
      for (int kt = 0; kt < 4; kt++) {          // x-even part
        union { bf16x8 v; __hip_bfloat162 h2[4]; } u;
#pragma unroll
        for (int i = 0; i < 4; i++) {
          int slot = kt * 16 + ((lq * 4 + i) ^ lr);
          float4 q = *(const float4*)(xsc + lr * 1024 + slot * 16);
          u.h2[i] = __float22bfloat162_rn(make_float2(q.x, q.z));
        }
        bf16x8 bfr0 = *(const bf16x8*)&wp[W1P_OFF + ((wid * 2 + 0) * 14 + kt) * 64 + l];
        bf16x8 bfr1 = *(const bf16x8*)&wp[W1P_OFF + ((wid * 2 + 1) * 14 + kt) * 64 + l];
        acc[0] = __builtin_amdgcn_mfma_f32_16x16x32_bf16(u.v, bfr0, acc[0], 0, 0, 0);
        acc[1] = __builtin_amdgcn_mfma_f32_16x16x32_bf16(u.v, bfr1, acc[1], 0, 0, 0);
      }
#pragma unroll 2
      for (int kh = 0; kh < 10; kh++) {         // h part
        int c0 = kh * 8 + lq * 2;
        int qd = c0 & ~15, mm = c0 & 15;
        float4 a = *(const float4*)(hsc + lr * 1280 + (qd | (mm ^ lr)) * 16);
        float4 b = *(const float4*)(hsc + lr * 1280 + (qd | ((mm + 1) ^ lr)) * 16);
        union { bf16x8 v; __hip_bfloat162 h2[4]; } u;
        u.h2[0] = __float22bfloat162_rn(make_float2(a.x, a.y));
        u.h2[1] = __float22bfloat162_rn(make_float2(a.z, a.w));
        u.h2[2] = __float22bfloat162_rn(make_float2(b.x, b.y));
        u.h2[3] = __float22bfloat162_rn(make_float2(b.z, b.w));
        int kt = kh + 4;
        bf16x8 bfr0 = *(const bf16x8*)&wp[W1P_OFF + ((wid * 2 + 0) * 14 + kt) * 64 + l];
        bf16x8 bfr1 = *(const bf16x8*)&wp[W1P_OFF + ((wid * 2 + 1) * 14 + kt) * 64 + l];
        acc[0] = __builtin_amdgcn_mfma_f32_16x16x32_bf16(u.v, bfr0, acc[0], 0, 0, 0);
        acc[1] = __builtin_amdgcn_mfma_f32_16x16x32_bf16(u.v, bfr1, acc[1], 0, 0, 0);
      }
#pragma unroll
      for (int nj = 0; nj < 2; nj++) {
        int col = wid * 32 + nj * 16 + lr;
        float bv = b1[col];
#pragma unroll
        for (int r = 0; r < 4; r++)
          a1[(lq * 4 + r) * AP + col] = f2bf(fmaxf(acc[nj][r] + bv, 0.f));
      }
    }
    __syncthreads();   // B1: a1 visible; h[cur] dead

    // ---- GEMM2: a2 = relu(a1 @ W2 + b2)   (a2 -> h[cur] region)
    {
      f32x4 acc[2] = {};
#pragma unroll
      for (int kt = 0; kt < 4; kt++) {
        bf16x8 afr = *(const bf16x8*)&a1[lr * AP + kt * 32 + lq * 8];
        bf16x8 bfr0 = *(const bf16x8*)&wp[W2P_OFF + ((wid * 2 + 0) * 4 + kt) * 64 + l];
        bf16x8 bfr1 = *(const bf16x8*)&wp[W2P_OFF + ((wid * 2 + 1) * 4 + kt) * 64 + l];
        acc[0] = __builtin_amdgcn_mfma_f32_16x16x32_bf16(afr, bfr0, acc[0], 0, 0, 0);
        acc[1] = __builtin_amdgcn_mfma_f32_16x16x32_bf16(afr, bfr1, acc[1], 0, 0, 0);
      }
#pragma unroll
      for (int nj = 0; nj < 2; nj++) {
        int col = wid * 32 + nj * 16 + lr;
        float bv = b2[col];
#pragma unroll
        for (int r = 0; r < 4; r++)
          a2[(lq * 4 + r) * AP + col] = f2bf(fmaxf(acc[nj][r] + bv, 0.f));
      }
    }
    __syncthreads();   // B2: a2 visible

    // ---- GEMM3: st = a2 @ W3 + b3
    f32x4 acc3[4] = {};
#pragma unroll
    for (int kt = 0; kt < 4; kt++) {
      bf16x8 afr = *(const bf16x8*)&a2[lr * AP + kt * 32 + lq * 8];
      bf16x8 bfrS0 = *(const bf16x8*)&wp[W3P_OFF + ((wid * 2 + 0) * 4 + kt) * 64 + l];
      bf16x8 bfrS1 = *(const bf16x8*)&wp[W3P_OFF + ((wid * 2 + 1) * 4 + kt) * 64 + l];
      bf16x8 bfrT0 = *(const bf16x8*)&wp[W3P_OFF + ((8 + wid * 2 + 0) * 4 + kt) * 64 + l];
      bf16x8 bfrT1 = *(const bf16x8*)&wp[W3P_OFF + ((8 + wid * 2 + 1) * 4 + kt) * 64 + l];
      acc3[0] = __builtin_amdgcn_mfma_f32_16x16x32_bf16(afr, bfrS0, acc3[0], 0, 0, 0);
      acc3[1] = __builtin_amdgcn_mfma_f32_16x16x32_bf16(afr, bfrS1, acc3[1], 0, 0, 0);
      acc3[2] = __builtin_amdgcn_mfma_f32_16x16x32_bf16(afr, bfrT0, acc3[2], 0, 0, 0);
      acc3[3] = __builtin_amdgcn_mfma_f32_16x16x32_bf16(afr, bfrT1, acc3[3], 0, 0, 0);
    }

    // ---- epilogue: x pair from LDS (exact f32, swizzled), tanh/exp, y, log_det
    float lp[4] = {0.f, 0.f, 0.f, 0.f};
#pragma unroll
    for (int nj = 0; nj < 2; nj++) {
      int colc = wid * 32 + nj * 16 + lr;
      float bs = b3[colc];
      float bt = b3[128 + colc];
#pragma unroll
      for (int r = 0; r < 4; r++) {
        int lrow = lq * 4 + r;
        float sv = tanh_fast(acc3[nj][r] + bs);
        float tv = acc3[nj + 2][r] + bt;
        lp[r] += sv;
        int cch = wid * 16 + nj * 8 + (lr >> 1);
        int slot = (cch & ~15) | ((cch & 15) ^ lrow);
        const float2 xv = *(const float2*)(xsc + lrow * 1024 + slot * 16 + (lr & 1) * 8);
        float2 o;
        o.x = xv.x;                              // exact pass-through
        o.y = xv.y * __expf(sv) + tv;
        *(float2*)(y + (size_t)(m0 + lrow) * 256 + 2 * colc) = o;
      }
    }

#pragma unroll
    for (int r = 0; r < 4; r++) {
      float v = lp[r];
      v += __shfl_xor(v, 1);
      v += __shfl_xor(v, 2);
      v += __shfl_xor(v, 4);
      v += __shfl_xor(v, 8);
      if (lr == 0) lsum[wid * BM + lq * 4 + r] = v;
    }
    __syncthreads();   // B3: lsum visible
    if (t < BM)
      ldet[m0 + t] = lsum[t] + lsum[BM + t] + lsum[2 * BM + t] + lsum[3 * BM + t];

    cur ^= 1;
  }
}

extern "C" void kernel_launch(void* const* d_in, const int* in_sizes, int n_in,
                              void* d_out, int out_size, void* d_ws, size_t ws_size,
                              hipStream_t stream) {
  const float* x  = (const float*)d_in[0];
  const float* h  = (const float*)d_in[1];
  const float* W1 = (const float*)d_in[2];
  const float* b1 = (const float*)d_in[3];
  const float* W2 = (const float*)d_in[4];
  const float* b2 = (const float*)d_in[5];
  const float* W3 = (const float*)d_in[6];
  const float* b3 = (const float*)d_in[7];
  float* y    = (float*)d_out;
  float* ldet = y + (size_t)B_ROWS * 256;
  uint4* wp   = (uint4*)d_ws;

  prepack_kernel<<<52, 256, 0, stream>>>(W1, W2, W3, wp);

  (void)hipFuncSetAttribute((const void*)fused_kernel,
                            hipFuncAttributeMaxDynamicSharedMemorySize, LDS_TOTAL);
  fused_kernel<<<GRID, 256, LDS_TOTAL, stream>>>(x, h, b1, b2, b3, wp, y, ldet);
}